// Round 1
// baseline (24.398 us; speedup 1.0000x reference)
//
#include <hip/hip_runtime.h>
#include <hip/hip_bf16.h>

#define BOX_SIZE 0.4f

// Each thread processes 4 points: loads 3 float4 (12 floats = 4 xyz triples),
// writes 1 float4 of distances. Fully coalesced 16B/lane loads and stores.
__global__ __launch_bounds__(256) void capudf_box_dist_kernel(
    const float4* __restrict__ in, float4* __restrict__ out, int n4) {
    int i = blockIdx.x * blockDim.x + threadIdx.x;
    if (i >= n4) return;

    float4 a = in[3 * i + 0];
    float4 b = in[3 * i + 1];
    float4 c = in[3 * i + 2];

    // point p components:
    // p0: a.x a.y a.z | p1: a.w b.x b.y | p2: b.z b.w c.x | p3: c.y c.z c.w
    float xs[4][3] = {
        {a.x, a.y, a.z},
        {a.w, b.x, b.y},
        {b.z, b.w, c.x},
        {c.y, c.z, c.w},
    };

    float r[4];
#pragma unroll
    for (int p = 0; p < 4; ++p) {
        float q0 = fabsf(xs[p][0]) - BOX_SIZE;
        float q1 = fabsf(xs[p][1]) - BOX_SIZE;
        float q2 = fabsf(xs[p][2]) - BOX_SIZE;
        float m  = fmaxf(fmaxf(q0, q1), q2);       // max_i q_i
        float r0 = fmaxf(q0, 0.0f);
        float r1 = fmaxf(q1, 0.0f);
        float r2 = fmaxf(q2, 0.0f);
        float s  = sqrtf(r0 * r0 + r1 * r1 + r2 * r2);
        // inside (all q_i < 0)  <=>  m < 0 : distance = -m
        // outside: sqrt of clamped components
        r[p] = (m < 0.0f) ? -m : s;
    }

    out[i] = make_float4(r[0], r[1], r[2], r[3]);
}

extern "C" void kernel_launch(void* const* d_in, const int* in_sizes, int n_in,
                              void* d_out, int out_size, void* d_ws, size_t ws_size,
                              hipStream_t stream) {
    const float4* in = (const float4*)d_in[0];
    float4* out = (float4*)d_out;

    // out_size = N points; each thread handles 4 points.
    int n4 = out_size / 4;  // N = 8388608 -> n4 = 2097152 (exact)
    int block = 256;
    int grid = (n4 + block - 1) / block;
    capudf_box_dist_kernel<<<grid, block, 0, stream>>>(in, out, n4);
}